// Round 15
// baseline (78.657 us; speedup 1.0000x reference)
//
#include <hip/hip_runtime.h>
#include <math.h>

typedef __attribute__((ext_vector_type(4))) float f32x4;
typedef __attribute__((ext_vector_type(16))) float f32x16;
typedef __attribute__((ext_vector_type(8))) short bf16x8;

namespace {
constexpr int kB = 2;
constexpr int kS = 1024;
constexpr int kD = 128;
constexpr float kScale = 0.08838834764831845f;   // 1/sqrt(128)
constexpr float kLog2e = 1.4426950408889634f;
constexpr float kFreqC = 0.20503692777194262f;   // ln(500000)/64
constexpr int kKPad = 136;  // fallback kernel pads
constexpr int kVPad = 72;

// workspace layout (bytes)
constexpr size_t kTabOff = 0;                       // float2[1024*64] = 512 KB
constexpr size_t kKOff = 512 * 1024;                // bf16 [2][8][1024][128]
constexpr size_t kVOff = kKOff + 4194304;           // bf16 [2][8][128][1024]
constexpr size_t kWsNeed = kVOff + 4194304;         // ~8.9 MB
}

#define VMCNT(n) asm volatile("s_waitcnt vmcnt(" #n ")" ::: "memory")

__device__ inline short f2bf(float f) {  // RNE float->bf16
  union { float f; unsigned u; } c{f};
  unsigned r = c.u + 0x7fffu + ((c.u >> 16) & 1u);
  return (short)(r >> 16);
}

__device__ inline unsigned pkbf(float a, float b) {  // (bf16(b)<<16)|bf16(a)
  unsigned r;
  asm("v_cvt_pk_bf16_f32 %0, %1, %2" : "=v"(r) : "v"(a), "v"(b));
  return r;
}

__device__ inline void gload16(const void* g, void* l) {
  __builtin_amdgcn_global_load_lds(
      (const __attribute__((address_space(1))) void*)g,
      (__attribute__((address_space(3))) void*)l, 16, 0, 0);
}

// tab[pos*64 + j] = (cos(pos*f_j), sin(pos*f_j))  (fallback path only)
__global__ __launch_bounds__(256) void rope_table_k(float2* __restrict__ tab) {
  int t = blockIdx.x * 256 + threadIdx.x;  // 1024*64
  int pos = t >> 6, j = t & 63;
  float ang = (float)pos * expf(-(float)j * kFreqC);
  float sn, cs;
  sincosf(ang, &sn, &cs);
  tab[t] = make_float2(cs, sn);
}

// Fused prepass (R11-verified): [0,1024) K-RoPE (inline sincos) -> bf16
// [b][h][s][d]; [1024,1536) V transpose -> [b][hkv][d][s] bf16;
// [1536,1792) cos/sin table.
__global__ __launch_bounds__(256) void prep_k(
    const float* __restrict__ k, const float* __restrict__ v,
    short* __restrict__ Kp, short* __restrict__ Vp, float2* __restrict__ tab) {
  __shared__ float Tl[64][68];
  int bid = blockIdx.x;
  if (bid < 1024) {
    int t2 = bid * 256 + threadIdx.x;  // 262144
    int j = (t2 & 15) * 4;
    int h = (t2 >> 4) & 7;
    int s = (t2 >> 7) & 1023;
    int b = t2 >> 17;
    size_t sidx = ((size_t)b * 1024 + s) * 1024 + h * 128 + j;
    size_t didx = (((size_t)b * 8 + h) * 1024 + s) * 128 + j;
    float4 x1 = *(const float4*)&k[sidx];
    float4 x2 = *(const float4*)&k[sidx + 64];
    float cs[4], sn[4];
#pragma unroll
    for (int jj = 0; jj < 4; ++jj) {
      float ang = (float)s * expf(-(float)(j + jj) * kFreqC);
      sincosf(ang, &sn[jj], &cs[jj]);
    }
    short4 y1, y2;
    y1.x = f2bf(x1.x * cs[0] - x2.x * sn[0]);
    y2.x = f2bf(x1.x * sn[0] + x2.x * cs[0]);
    y1.y = f2bf(x1.y * cs[1] - x2.y * sn[1]);
    y2.y = f2bf(x1.y * sn[1] + x2.y * cs[1]);
    y1.z = f2bf(x1.z * cs[2] - x2.z * sn[2]);
    y2.z = f2bf(x1.z * sn[2] + x2.z * cs[2]);
    y1.w = f2bf(x1.w * cs[3] - x2.w * sn[3]);
    y2.w = f2bf(x1.w * sn[3] + x2.w * cs[3]);
    *(short4*)&Kp[didx] = y1;
    *(short4*)&Kp[didx + 64] = y2;
  } else if (bid < 1536) {
    int blk = bid - 1024;
    int bh = blk >> 5;            // 0..15 = b*8+h
    int rem = blk & 31;
    int s0 = (rem >> 1) * 64;
    int d0 = (rem & 1) * 64;
    int t = threadIdx.x;
#pragma unroll
    for (int i = 0; i < 4; ++i) {
      int srow = i * 16 + (t >> 4);
      int scol = (t & 15) * 4;
      float4 x = *(const float4*)&v[((size_t)(bh >> 3) * 1024 + s0 + srow) * 1024 +
                                    (bh & 7) * 128 + d0 + scol];
      *(float4*)&Tl[srow][scol] = x;
    }
    __syncthreads();
#pragma unroll
    for (int i = 0; i < 4; ++i) {
      int drow = i * 16 + (t >> 4);
      int sq = (t & 15) * 4;
      short4 y;
      y.x = f2bf(Tl[sq + 0][drow]);
      y.y = f2bf(Tl[sq + 1][drow]);
      y.z = f2bf(Tl[sq + 2][drow]);
      y.w = f2bf(Tl[sq + 3][drow]);
      *(short4*)&Vp[((size_t)bh * 128 + d0 + drow) * 1024 + s0 + sq] = y;
    }
  } else {
    int t = (bid - 1536) * 256 + threadIdx.x;  // 65536
    int pos = t >> 6, j = t & 63;
    float ang = (float)pos * expf(-(float)j * kFreqC);
    float sn, cs;
    sincosf(ang, &sn, &cs);
    tab[t] = make_float2(cs, sn);
  }
}

// Main attention: 64-row q-tiles (1024 blocks, longest-first); waves split
// (qsub 2 x key-half 2) with per-wave online softmax, merged once via LDS
// overlay (R11-verified machinery). K double-buffered (32 KB) + V SINGLE-
// buffered (16 KB) -> ~50 KB LDS -> 3 blocks/CU = 12 waves. Per slot:
// vmcnt(0) [K(t)] -> barrier -> issue V(t), K(t+1) -> QK -> softmax ->
// vmcnt(4) [V(t); K(t+1) in flight] -> barrier -> PV. V latency hides under
// QK+softmax (T14 intra-slot).
__global__ __launch_bounds__(256, 2) void attnv1_k(
    const float* __restrict__ q, const short* __restrict__ Kp,
    const short* __restrict__ Vp, const float2* __restrict__ tab,
    float* __restrict__ out) {
  __shared__ char Kbuf[2][16384];  // K tile [64][128]bf16, swizzled
  __shared__ char Vbuf[16384];     // Vt tile [128][64]bf16, swizzled (single)
  __shared__ float Pml[2][128];    // merge m/l scratch per qsub

  const int tid = threadIdx.x;
  const int w = tid >> 6;
  const int lane = tid & 63;
  const int l31 = lane & 31;
  const int hi5 = lane >> 5;
  const int qsub = w & 1;          // 32-row q-sub-tile within the 64-row tile
  const int kh = w >> 1;           // 32-key half within the 64-key tile
  const int qt = 15 - (int)blockIdx.x;  // longest dispatched first
  const int hq = blockIdx.y;
  const int b = blockIdx.z;
  const int hkv = hq >> 2;
  const int q0 = qt * 64;
  const int nk = qt + 1;
  const int qrow = q0 + qsub * 32 + l31;   // this lane's q row

  const char* Kh = (const char*)(Kp + ((size_t)b * 8 + hkv) * 1024 * 128);
  const char* Vh = (const char*)(Vp + ((size_t)b * 8 + hkv) * 128 * 1024);
  float* Lf = (float*)Kbuf;        // merge overlay (post-loop): 2 x 4096 floats

#define STAGE_K(k0_, bufi_)                                                   \
  {                                                                           \
    char* Kd = Kbuf[bufi_];                                                   \
    _Pragma("unroll") for (int ii = 0; ii < 4; ++ii) {                        \
      int i = w * 4 + ii;                                                     \
      int row = i * 4 + (lane >> 4);                                          \
      int srcb = ((k0_) + row) * 256 + (((lane & 15) * 16) ^ ((row & 7) << 4)); \
      gload16(Kh + srcb, Kd + i * 1024);                                      \
    }                                                                         \
  }
#define STAGE_V(k0_)                                                          \
  {                                                                           \
    char* Vd = Vbuf;                                                          \
    _Pragma("unroll") for (int ii = 0; ii < 4; ++ii) {                        \
      int i = w * 4 + ii;                                                     \
      int d = i * 8 + (lane >> 3);                                            \
      int srcb = d * 2048 + (k0_) * 2 + (((lane & 7) * 16) ^ ((d & 7) << 4)); \
      gload16(Vh + srcb, Vd + i * 1024);                                      \
    }                                                                         \
  }

  STAGE_K(0, 0);  // prologue: K(0); latency hidden under Q RoPE below

  // ---- Q B-fragments: RoPE in registers ----
  const float* qp = q + ((size_t)b * 1024 + qrow) * 4096 + hq * 128;
  const float2* tp = tab + (size_t)qrow * 64;
  bf16x8 qB[8];
#pragma unroll
  for (int g = 0; g < 4; ++g) {
    int jb = g * 16 + hi5 * 8;
    float4 x1a = *(const float4*)&qp[jb];
    float4 x1b = *(const float4*)&qp[jb + 4];
    float4 x2a = *(const float4*)&qp[jb + 64];
    float4 x2b = *(const float4*)&qp[jb + 68];
    float4 t0 = *(const float4*)&tp[jb];
    float4 t1 = *(const float4*)&tp[jb + 2];
    float4 t2 = *(const float4*)&tp[jb + 4];
    float4 t3 = *(const float4*)&tp[jb + 6];
    float lo[8], hb[8];
    lo[0] = (x1a.x * t0.x - x2a.x * t0.y) * kScale;
    hb[0] = (x1a.x * t0.y + x2a.x * t0.x) * kScale;
    lo[1] = (x1a.y * t0.z - x2a.y * t0.w) * kScale;
    hb[1] = (x1a.y * t0.w + x2a.y * t0.z) * kScale;
    lo[2] = (x1a.z * t1.x - x2a.z * t1.y) * kScale;
    hb[2] = (x1a.z * t1.y + x2a.z * t1.x) * kScale;
    lo[3] = (x1a.w * t1.z - x2a.w * t1.w) * kScale;
    hb[3] = (x1a.w * t1.w + x2a.w * t1.z) * kScale;
    lo[4] = (x1b.x * t2.x - x2b.x * t2.y) * kScale;
    hb[4] = (x1b.x * t2.y + x2b.x * t2.x) * kScale;
    lo[5] = (x1b.y * t2.z - x2b.y * t2.w) * kScale;
    hb[5] = (x1b.y * t2.w + x2b.y * t2.z) * kScale;
    lo[6] = (x1b.z * t3.x - x2b.z * t3.y) * kScale;
    hb[6] = (x1b.z * t3.y + x2b.z * t3.x) * kScale;
    lo[7] = (x1b.w * t3.z - x2b.w * t3.w) * kScale;
    hb[7] = (x1b.w * t3.w + x2b.w * t3.z) * kScale;
    union { unsigned u[4]; bf16x8 v; } A, C;
#pragma unroll
    for (int ww = 0; ww < 4; ++ww) {
      A.u[ww] = pkbf(lo[2 * ww], lo[2 * ww + 1]);
      C.u[ww] = pkbf(hb[2 * ww], hb[2 * ww + 1]);
    }
    qB[g] = A.v;
    qB[g + 4] = C.v;
  }

  float m = -3e38f, l = 0.f;
  f32x16 acc[4];
#pragma unroll
  for (int dt = 0; dt < 4; ++dt)
#pragma unroll
    for (int e = 0; e < 16; ++e) acc[dt][e] = 0.f;

  int buf = 0;
  for (int t = 0; t < nk; ++t) {
    VMCNT(0);   // K(t) landed (4 loads; issued prologue or mid-slot t-1)
    __builtin_amdgcn_sched_barrier(0);
    __builtin_amdgcn_s_barrier();   // Vbuf free (PV(t-1) done); K[buf] ready
    __builtin_amdgcn_sched_barrier(0);

    STAGE_V(t * 64);                               // 4 loads (oldest)
    if (t < nk - 1) STAGE_K((t + 1) * 64, buf ^ 1);  // 4 loads (newest)

    const int skip = (t == qt && qsub == 0 && kh == 1);
    f32x16 sc;
    if (!skip) {
      const char* Ks = Kbuf[buf];

      // ---- QK^T swapped over this wave's 32 keys ----
#pragma unroll
      for (int e = 0; e < 16; ++e) sc[e] = 0.f;
      const int krow = kh * 32 + l31;
      const int kswz = (l31 & 7) << 4;
      __builtin_amdgcn_s_setprio(1);
#pragma unroll
      for (int c = 0; c < 8; ++c) {
        bf16x8 kf = *(const bf16x8*)(Ks + krow * 256 +
                                     ((c * 32 + hi5 * 16) ^ kswz));
        sc = __builtin_amdgcn_mfma_f32_32x32x16_bf16(kf, qB[c], sc, 0, 0, 0);
      }
      __builtin_amdgcn_s_setprio(0);

      // ---- diagonal mask: only when this wave sits on the diagonal ----
      if (t == qt && qsub == kh) {
        int kb = t * 64 + kh * 32 + 4 * hi5;
#pragma unroll
        for (int r = 0; r < 16; ++r)
          if (kb + (r & 3) + 8 * (r >> 2) > qrow) sc[r] = -3e38f;
      }

      // ---- per-wave online softmax (lane pair {l, l^32} owns q=l31) ----
      float tv = -3e38f;
#pragma unroll
      for (int r = 0; r < 16; ++r) tv = fmaxf(tv, sc[r]);
      tv = fmaxf(tv, __shfl_xor(tv, 32));
      if (!__all(tv <= m + 8.f)) {   // defer-max THR=8
        float mn = fmaxf(m, tv);
        float al = exp2f((m - mn) * kLog2e);
        m = mn;
        l *= al;
#pragma unroll
        for (int r = 0; r < 16; ++r) {
          float alr = __shfl(al, (r & 3) + 8 * (r >> 2) + 4 * hi5);
          acc[0][r] *= alr;
          acc[1][r] *= alr;
          acc[2][r] *= alr;
          acc[3][r] *= alr;
        }
      }
      float rs = 0.f;
#pragma unroll
      for (int r = 0; r < 16; ++r) {
        sc[r] = exp2f((sc[r] - m) * kLog2e);
        rs += sc[r];
      }
      rs += __shfl_xor(rs, 32);
      l += rs;
    }

    // ---- all waves: wait own V(t) loads (K(t+1) stays in flight) ----
    if (t < nk - 1) { VMCNT(4); } else { VMCNT(0); }
    __builtin_amdgcn_sched_barrier(0);
    __builtin_amdgcn_s_barrier();   // all waves' V(t) writes landed
    __builtin_amdgcn_sched_barrier(0);

    if (!skip) {
      // ---- P -> A-frag (cvt_pk + permlane32_swap) fused with PV ----
      __builtin_amdgcn_s_setprio(1);
#define PV_CHUNK(CI)                                                          \
      {                                                                       \
        unsigned p0 = pkbf(sc[8 * (CI) + 0], sc[8 * (CI) + 1]);               \
        unsigned p1 = pkbf(sc[8 * (CI) + 2], sc[8 * (CI) + 3]);               \
        unsigned p2 = pkbf(sc[8 * (CI) + 4], sc[8 * (CI) + 5]);               \
        unsigned p3 = pkbf(sc[8 * (CI) + 6], sc[8 * (CI) + 7]);               \
        asm("v_permlane32_swap_b32 %0, %1" : "+v"(p0), "+v"(p2));             \
        asm("v_permlane32_swap_b32 %0, %1" : "+v"(p1), "+v"(p3));             \
        union { unsigned u[4]; bf16x8 v; } pa;                                \
        pa.u[0] = p0; pa.u[1] = p1; pa.u[2] = p2; pa.u[3] = p3;               \
        int ko = (kh * 2 + (CI)) * 32 + hi5 * 16;                             \
        _Pragma("unroll") for (int dt = 0; dt < 4; ++dt) {                    \
          int d = dt * 32 + l31;                                              \
          bf16x8 vf = *(const bf16x8*)(Vbuf + d * 128 + (ko ^ ((d & 7) << 4))); \
          acc[dt] = __builtin_amdgcn_mfma_f32_32x32x16_bf16(pa.v, vf,         \
                                                            acc[dt], 0, 0, 0); \
        }                                                                     \
      }
      PV_CHUNK(0)
      PV_CHUNK(1)
#undef PV_CHUNK
      __builtin_amdgcn_s_setprio(0);
    }
    buf ^= 1;
  }

  // ---- merge the two key-halves per q-sub-tile (overlay on Kbuf) ----
  // All QK reads of Kbuf finished before the last mid-slot barrier; PV reads
  // only Vbuf -> kh=1 waves may write the overlay immediately.
  const int mbase = qsub * 4096;
  if (kh == 1) {
#pragma unroll
    for (int dt = 0; dt < 4; ++dt)
#pragma unroll
      for (int c4 = 0; c4 < 4; ++c4) {
        f32x4 v4 = {acc[dt][c4 * 4], acc[dt][c4 * 4 + 1],
                    acc[dt][c4 * 4 + 2], acc[dt][c4 * 4 + 3]};
        *(f32x4*)&Lf[mbase + (dt * 4 + c4) * 256 + lane * 4] = v4;
      }
    Pml[qsub][lane] = m;
    Pml[qsub][64 + lane] = l;
  }
  __syncthreads();
  if (kh == 0) {
    float m2 = Pml[qsub][lane];
    float l2 = Pml[qsub][64 + lane];
    float mm = fmaxf(m, m2);
    float a1 = exp2f((m - mm) * kLog2e);
    float a2 = exp2f((m2 - mm) * kLog2e);
    float lt = l * a1 + l2 * a2;
    float linv = 1.f / lt;
    const size_t obase =
        ((size_t)b * 1024 + q0 + qsub * 32) * 4096 + (size_t)hq * 128;
#pragma unroll
    for (int r = 0; r < 16; ++r) {
      int rq = (r & 3) + 8 * (r >> 2) + 4 * hi5;   // q row in [0,32)
      float a1r = __shfl(a1, rq);
      float a2r = __shfl(a2, rq);
      float ilr = __shfl(linv, rq);
      float* orow = out + obase + (size_t)rq * 4096 + l31;
#pragma unroll
      for (int dt = 0; dt < 4; ++dt) {
        float o2 = Lf[mbase + (dt * 4 + (r >> 2)) * 256 + lane * 4 + (r & 3)];
        orow[dt * 32] = (acc[dt][r] * a1r + o2 * a2r) * ilr;
      }
    }
  }
#undef STAGE_K
#undef STAGE_V
}

// ---------------- fallback (small-ws path) ----------------
template <bool USE_TAB>
__global__ __launch_bounds__(256) void attn_k(
    const float* __restrict__ q, const float* __restrict__ k,
    const float* __restrict__ v, const float2* __restrict__ tab,
    float* __restrict__ out) {
  __shared__ short Ksf[64][kKPad];
  __shared__ short Vtf[kD][kVPad];
  __shared__ short Qbuf[64 * kKPad];
  const int tid = threadIdx.x;
  const int w = tid >> 6;
  const int lane = tid & 63;
  const int lrow = lane & 15;
  const int lk8 = (lane >> 4) * 8;
  const int qt = (int)gridDim.x - 1 - (int)blockIdx.x;
  const int hq = blockIdx.y;
  const int b = blockIdx.z;
  const int hkv = hq >> 2;
  const int q0 = qt * 64;
  const float* qb = q + (size_t)b * kS * 4096 + hq * kD;
  const float* kb = k + (size_t)b * kS * 1024 + hkv * kD;
  const float* vb = v + (size_t)b * kS * 1024 + hkv * kD;
#pragma unroll
  for (int it = 0; it < 16; ++it) {
    int pi = tid + it * 256;
    int row = pi >> 6, j = pi & 63;
    int pos = q0 + row;
    float x1 = qb[(size_t)pos * 4096 + j];
    float x2 = qb[(size_t)pos * 4096 + j + 64];
    float c, s;
    if (USE_TAB) { float2 t2 = tab[(pos << 6) + j]; c = t2.x; s = t2.y; }
    else { float ang = (float)pos * __expf(-(float)j * kFreqC); __sincosf(ang, &s, &c); }
    Qbuf[row * kKPad + j]      = f2bf((x1 * c - x2 * s) * kScale);
    Qbuf[row * kKPad + j + 64] = f2bf((x1 * s + x2 * c) * kScale);
  }
  __syncthreads();
  bf16x8 qf[4];
#pragma unroll
  for (int d = 0; d < 4; ++d)
    qf[d] = *(const bf16x8*)&Qbuf[(w * 16 + lrow) * kKPad + d * 32 + lk8];
  __syncthreads();
  short* myP = Qbuf + w * 16 * kVPad;
  float mS[4] = {-3e38f, -3e38f, -3e38f, -3e38f};
  float lS[4] = {0.f, 0.f, 0.f, 0.f};
  f32x4 acc[8];
#pragma unroll
  for (int dt = 0; dt < 8; ++dt) acc[dt] = f32x4{0.f, 0.f, 0.f, 0.f};
  for (int kt = 0; kt <= qt; ++kt) {
    const int k0 = kt * 64;
#pragma unroll
    for (int it = 0; it < 16; ++it) {
      int pi = tid + it * 256;
      int row = pi >> 6, j = pi & 63;
      int pos = k0 + row;
      float x1 = kb[(size_t)pos * 1024 + j];
      float x2 = kb[(size_t)pos * 1024 + j + 64];
      float c, s;
      if (USE_TAB) { float2 t2 = tab[(pos << 6) + j]; c = t2.x; s = t2.y; }
      else { float ang = (float)pos * __expf(-(float)j * kFreqC); __sincosf(ang, &s, &c); }
      Ksf[row][j]      = f2bf(x1 * c - x2 * s);
      Ksf[row][j + 64] = f2bf(x1 * s + x2 * c);
    }
#pragma unroll
    for (int it = 0; it < 8; ++it) {
      int f = (tid + it * 256) * 4;
      int row = f >> 7, col = f & 127;
      const float4 v4 = *(const float4*)(vb + (size_t)(k0 + row) * 1024 + col);
      Vtf[col + 0][row] = f2bf(v4.x);
      Vtf[col + 1][row] = f2bf(v4.y);
      Vtf[col + 2][row] = f2bf(v4.z);
      Vtf[col + 3][row] = f2bf(v4.w);
    }
    __syncthreads();
    f32x4 sc[4];
#pragma unroll
    for (int ct = 0; ct < 4; ++ct) {
      sc[ct] = f32x4{0.f, 0.f, 0.f, 0.f};
#pragma unroll
      for (int d = 0; d < 4; ++d) {
        bf16x8 kf = *(const bf16x8*)&Ksf[ct * 16 + lrow][d * 32 + lk8];
        sc[ct] = __builtin_amdgcn_mfma_f32_16x16x32_bf16(qf[d], kf, sc[ct], 0, 0, 0);
      }
    }
    if (kt == qt) {
#pragma unroll
      for (int ct = 0; ct < 4; ++ct) {
        int col = ct * 16 + lrow;
#pragma unroll
        for (int r = 0; r < 4; ++r) {
          int row = w * 16 + (lane >> 4) * 4 + r;
          if (col > row) sc[ct][r] = -3e38f;
        }
      }
    }
#pragma unroll
    for (int r = 0; r < 4; ++r) {
      float t = fmaxf(fmaxf(sc[0][r], sc[1][r]), fmaxf(sc[2][r], sc[3][r]));
      t = fmaxf(t, __shfl_xor(t, 1));
      t = fmaxf(t, __shfl_xor(t, 2));
      t = fmaxf(t, __shfl_xor(t, 4));
      t = fmaxf(t, __shfl_xor(t, 8));
      float mn = fmaxf(mS[r], t);
      float al = exp2f((mS[r] - mn) * kLog2e);
      float rs = 0.f;
#pragma unroll
      for (int ct = 0; ct < 4; ++ct) {
        float p = exp2f((sc[ct][r] - mn) * kLog2e);
        sc[ct][r] = p;
        rs += p;
      }
      rs += __shfl_xor(rs, 1);
      rs += __shfl_xor(rs, 2);
      rs += __shfl_xor(rs, 4);
      rs += __shfl_xor(rs, 8);
      lS[r] = lS[r] * al + rs;
      mS[r] = mn;
#pragma unroll
      for (int dt = 0; dt < 8; ++dt) acc[dt][r] *= al;
    }
#pragma unroll
    for (int ct = 0; ct < 4; ++ct)
#pragma unroll
      for (int r = 0; r < 4; ++r)
        myP[((lane >> 4) * 4 + r) * kVPad + ct * 16 + lrow] = f2bf(sc[ct][r]);
#pragma unroll
    for (int ks = 0; ks < 2; ++ks) {
      bf16x8 pf = *(const bf16x8*)&myP[lrow * kVPad + ks * 32 + lk8];
#pragma unroll
      for (int dt = 0; dt < 8; ++dt) {
        bf16x8 vf = *(const bf16x8*)&Vtf[dt * 16 + lrow][ks * 32 + lk8];
        acc[dt] = __builtin_amdgcn_mfma_f32_16x16x32_bf16(pf, vf, acc[dt], 0, 0, 0);
      }
    }
    __syncthreads();
  }
  float il[4];
#pragma unroll
  for (int r = 0; r < 4; ++r) il[r] = 1.f / lS[r];
  float* ob = out + ((size_t)b * kS + q0 + w * 16) * 4096 + hq * kD;
#pragma unroll
  for (int dt = 0; dt < 8; ++dt)
#pragma unroll
    for (int r = 0; r < 4; ++r)
      ob[((lane >> 4) * 4 + r) * 4096 + dt * 16 + lrow] = acc[dt][r] * il[r];
}

extern "C" void kernel_launch(void* const* d_in, const int* in_sizes, int n_in,
                              void* d_out, int out_size, void* d_ws, size_t ws_size,
                              hipStream_t stream) {
  const float* q = (const float*)d_in[0];
  const float* k = (const float*)d_in[1];
  const float* v = (const float*)d_in[2];
  float* out = (float*)d_out;

  if (ws_size >= kWsNeed) {
    float2* tab = (float2*)((char*)d_ws + kTabOff);
    short* Kp = (short*)((char*)d_ws + kKOff);
    short* Vp = (short*)((char*)d_ws + kVOff);
    prep_k<<<1792, 256, 0, stream>>>(k, v, Kp, Vp, tab);
    dim3 grid(16, 32, kB);  // 1024 blocks, longest-first; 3 resident/CU
    attnv1_k<<<grid, 256, 0, stream>>>(q, Kp, Vp, tab, out);
  } else if (ws_size >= 512 * 1024) {
    float2* tab = (float2*)d_ws;
    rope_table_k<<<256, 256, 0, stream>>>(tab);
    dim3 grid(16, 32, kB);
    attn_k<true><<<grid, 256, 0, stream>>>(q, k, v, tab, out);
  } else {
    dim3 grid(16, 32, kB);
    attn_k<false><<<grid, 256, 0, stream>>>(q, k, v, nullptr, out);
  }
}

// Round 16
// 59.525 us; speedup vs baseline: 1.3214x; 1.3214x over previous
//
#include <hip/hip_runtime.h>
#include <math.h>

typedef __attribute__((ext_vector_type(4))) float f32x4;
typedef __attribute__((ext_vector_type(16))) float f32x16;
typedef __attribute__((ext_vector_type(8))) short bf16x8;

namespace {
constexpr int kB = 2;
constexpr int kS = 1024;
constexpr int kD = 128;
constexpr float kScale = 0.08838834764831845f;   // 1/sqrt(128)
constexpr float kLog2e = 1.4426950408889634f;
constexpr float kFreqC = 0.20503692777194262f;   // ln(500000)/64
constexpr int kKPad = 136;  // fallback kernel pads
constexpr int kVPad = 72;

// workspace layout (bytes)
constexpr size_t kTabOff = 0;                       // float2[1024*64] = 512 KB
constexpr size_t kKOff = 512 * 1024;                // bf16 [2][8][1024][128]
constexpr size_t kVOff = kKOff + 4194304;           // bf16 [2][8][128][1024]
constexpr size_t kWsNeed = kVOff + 4194304;         // ~8.9 MB
}

#define VMCNT(n) asm volatile("s_waitcnt vmcnt(" #n ")" ::: "memory")

__device__ inline short f2bf(float f) {  // RNE float->bf16
  union { float f; unsigned u; } c{f};
  unsigned r = c.u + 0x7fffu + ((c.u >> 16) & 1u);
  return (short)(r >> 16);
}

__device__ inline unsigned pkbf(float a, float b) {  // (bf16(b)<<16)|bf16(a)
  unsigned r;
  asm("v_cvt_pk_bf16_f32 %0, %1, %2" : "=v"(r) : "v"(a), "v"(b));
  return r;
}

__device__ inline void gload16(const void* g, void* l) {
  __builtin_amdgcn_global_load_lds(
      (const __attribute__((address_space(1))) void*)g,
      (__attribute__((address_space(3))) void*)l, 16, 0, 0);
}

// tab[pos*64 + j] = (cos(pos*f_j), sin(pos*f_j))  (fallback path only)
__global__ __launch_bounds__(256) void rope_table_k(float2* __restrict__ tab) {
  int t = blockIdx.x * 256 + threadIdx.x;  // 1024*64
  int pos = t >> 6, j = t & 63;
  float ang = (float)pos * expf(-(float)j * kFreqC);
  float sn, cs;
  sincosf(ang, &sn, &cs);
  tab[t] = make_float2(cs, sn);
}

// Fused prepass (R11-verified): [0,1024) K-RoPE (inline sincos) -> bf16
// [b][h][s][d]; [1024,1536) V transpose -> [b][hkv][d][s] bf16;
// [1536,1792) cos/sin table.
__global__ __launch_bounds__(256) void prep_k(
    const float* __restrict__ k, const float* __restrict__ v,
    short* __restrict__ Kp, short* __restrict__ Vp, float2* __restrict__ tab) {
  __shared__ float Tl[64][68];
  int bid = blockIdx.x;
  if (bid < 1024) {
    int t2 = bid * 256 + threadIdx.x;  // 262144
    int j = (t2 & 15) * 4;
    int h = (t2 >> 4) & 7;
    int s = (t2 >> 7) & 1023;
    int b = t2 >> 17;
    size_t sidx = ((size_t)b * 1024 + s) * 1024 + h * 128 + j;
    size_t didx = (((size_t)b * 8 + h) * 1024 + s) * 128 + j;
    float4 x1 = *(const float4*)&k[sidx];
    float4 x2 = *(const float4*)&k[sidx + 64];
    float cs[4], sn[4];
#pragma unroll
    for (int jj = 0; jj < 4; ++jj) {
      float ang = (float)s * expf(-(float)(j + jj) * kFreqC);
      sincosf(ang, &sn[jj], &cs[jj]);
    }
    short4 y1, y2;
    y1.x = f2bf(x1.x * cs[0] - x2.x * sn[0]);
    y2.x = f2bf(x1.x * sn[0] + x2.x * cs[0]);
    y1.y = f2bf(x1.y * cs[1] - x2.y * sn[1]);
    y2.y = f2bf(x1.y * sn[1] + x2.y * cs[1]);
    y1.z = f2bf(x1.z * cs[2] - x2.z * sn[2]);
    y2.z = f2bf(x1.z * sn[2] + x2.z * cs[2]);
    y1.w = f2bf(x1.w * cs[3] - x2.w * sn[3]);
    y2.w = f2bf(x1.w * sn[3] + x2.w * cs[3]);
    *(short4*)&Kp[didx] = y1;
    *(short4*)&Kp[didx + 64] = y2;
  } else if (bid < 1536) {
    int blk = bid - 1024;
    int bh = blk >> 5;            // 0..15 = b*8+h
    int rem = blk & 31;
    int s0 = (rem >> 1) * 64;
    int d0 = (rem & 1) * 64;
    int t = threadIdx.x;
#pragma unroll
    for (int i = 0; i < 4; ++i) {
      int srow = i * 16 + (t >> 4);
      int scol = (t & 15) * 4;
      float4 x = *(const float4*)&v[((size_t)(bh >> 3) * 1024 + s0 + srow) * 1024 +
                                    (bh & 7) * 128 + d0 + scol];
      *(float4*)&Tl[srow][scol] = x;
    }
    __syncthreads();
#pragma unroll
    for (int i = 0; i < 4; ++i) {
      int drow = i * 16 + (t >> 4);
      int sq = (t & 15) * 4;
      short4 y;
      y.x = f2bf(Tl[sq + 0][drow]);
      y.y = f2bf(Tl[sq + 1][drow]);
      y.z = f2bf(Tl[sq + 2][drow]);
      y.w = f2bf(Tl[sq + 3][drow]);
      *(short4*)&Vp[((size_t)bh * 128 + d0 + drow) * 1024 + s0 + sq] = y;
    }
  } else {
    int t = (bid - 1536) * 256 + threadIdx.x;  // 65536
    int pos = t >> 6, j = t & 63;
    float ang = (float)pos * expf(-(float)j * kFreqC);
    float sn, cs;
    sincosf(ang, &sn, &cs);
    tab[t] = make_float2(cs, sn);
  }
}

// Main attention (R8/R14-verified best): 32x32x16 MFMA, 128-row q-tile
// (32/wave), KT=64 K/V double-buffer via swizzled global_load_lds + counted
// vmcnt. Swapped QK^T -> per-lane P row; softmax in registers (1 cross-lane
// op); P->A-frag via cvt_pk + permlane32_swap. launch_bounds(256,2):
// VGPR=92, no spill (the only safe bound for this state size — (256,3) and
// (512,4) both collapsed codegen to scratch-spilling, R12/R13).
__global__ __launch_bounds__(256, 2) void attn32_k(
    const float* __restrict__ q, const short* __restrict__ Kp,
    const short* __restrict__ Vp, const float2* __restrict__ tab,
    float* __restrict__ out) {
  __shared__ char KV[2][32768];  // per buf: K [64][128]bf16 | Vt [128][64]bf16

  const int tid = threadIdx.x;
  const int w = tid >> 6;
  const int lane = tid & 63;
  const int l31 = lane & 31;
  const int hi5 = lane >> 5;
  // complementary-qt co-residency: blocks differing only in bz share a CU slot
  // and get qt summing to 7 -> roughly uniform per-CU work.
  const int f = ((int)blockIdx.x + (int)blockIdx.y) & 7;
  const int b = blockIdx.z;
  const int qt = b ? (7 - f) : f;
  const int hq = blockIdx.y;
  const int hkv = hq >> 2;
  const int q0 = qt * 128;
  const int nk = 2 * (qt + 1);

  const char* Kh = (const char*)(Kp + ((size_t)b * 8 + hkv) * 1024 * 128);
  const char* Vh = (const char*)(Vp + ((size_t)b * 8 + hkv) * 128 * 1024);

#define STAGE(k0_, bufi_)                                                     \
  {                                                                           \
    char* Kd = KV[bufi_];                                                     \
    char* Vd = KV[bufi_] + 16384;                                             \
    _Pragma("unroll") for (int ii = 0; ii < 4; ++ii) {                        \
      int i = w * 4 + ii;                                                     \
      int row = i * 4 + (lane >> 4);                                          \
      int srcb = ((k0_) + row) * 256 + (((lane & 15) * 16) ^ ((row & 7) << 4)); \
      gload16(Kh + srcb, Kd + i * 1024);                                      \
    }                                                                         \
    _Pragma("unroll") for (int ii = 0; ii < 4; ++ii) {                        \
      int i = w * 4 + ii;                                                     \
      int d = i * 8 + (lane >> 3);                                            \
      int srcb = d * 2048 + (k0_) * 2 + (((lane & 7) * 16) ^ ((d & 7) << 4)); \
      gload16(Vh + srcb, Vd + i * 1024);                                      \
    }                                                                         \
  }

  STAGE(0, 0);  // prologue stage; latency hidden under Q RoPE below

  // ---- Q B-fragments: RoPE in registers. qB[c] = Q[q=l31][16c+8*hi5 .. +7] ----
  const int qrow = q0 + w * 32 + l31;
  const float* qp = q + ((size_t)b * 1024 + qrow) * 4096 + hq * 128;
  const float2* tp = tab + (size_t)qrow * 64;
  bf16x8 qB[8];
#pragma unroll
  for (int g = 0; g < 4; ++g) {
    int jb = g * 16 + hi5 * 8;
    float4 x1a = *(const float4*)&qp[jb];
    float4 x1b = *(const float4*)&qp[jb + 4];
    float4 x2a = *(const float4*)&qp[jb + 64];
    float4 x2b = *(const float4*)&qp[jb + 68];
    float4 t0 = *(const float4*)&tp[jb];
    float4 t1 = *(const float4*)&tp[jb + 2];
    float4 t2 = *(const float4*)&tp[jb + 4];
    float4 t3 = *(const float4*)&tp[jb + 6];
    float lo[8], hb[8];
    lo[0] = (x1a.x * t0.x - x2a.x * t0.y) * kScale;
    hb[0] = (x1a.x * t0.y + x2a.x * t0.x) * kScale;
    lo[1] = (x1a.y * t0.z - x2a.y * t0.w) * kScale;
    hb[1] = (x1a.y * t0.w + x2a.y * t0.z) * kScale;
    lo[2] = (x1a.z * t1.x - x2a.z * t1.y) * kScale;
    hb[2] = (x1a.z * t1.y + x2a.z * t1.x) * kScale;
    lo[3] = (x1a.w * t1.z - x2a.w * t1.w) * kScale;
    hb[3] = (x1a.w * t1.w + x2a.w * t1.z) * kScale;
    lo[4] = (x1b.x * t2.x - x2b.x * t2.y) * kScale;
    hb[4] = (x1b.x * t2.y + x2b.x * t2.x) * kScale;
    lo[5] = (x1b.y * t2.z - x2b.y * t2.w) * kScale;
    hb[5] = (x1b.y * t2.w + x2b.y * t2.z) * kScale;
    lo[6] = (x1b.z * t3.x - x2b.z * t3.y) * kScale;
    hb[6] = (x1b.z * t3.y + x2b.z * t3.x) * kScale;
    lo[7] = (x1b.w * t3.z - x2b.w * t3.w) * kScale;
    hb[7] = (x1b.w * t3.w + x2b.w * t3.z) * kScale;
    union { unsigned u[4]; bf16x8 v; } A, C;
#pragma unroll
    for (int ww = 0; ww < 4; ++ww) {
      A.u[ww] = pkbf(lo[2 * ww], lo[2 * ww + 1]);
      C.u[ww] = pkbf(hb[2 * ww], hb[2 * ww + 1]);
    }
    qB[g] = A.v;
    qB[g + 4] = C.v;
  }

  float m = -3e38f, l = 0.f;
  f32x16 acc[4];
#pragma unroll
  for (int dt = 0; dt < 4; ++dt)
#pragma unroll
    for (int e = 0; e < 16; ++e) acc[dt][e] = 0.f;

  int buf = 0;
  for (int t = 0; t < nk; ++t) {
    if (t < nk - 1) {
      STAGE((t + 1) * 64, buf ^ 1);
      VMCNT(8);   // tile-t loads done; tile-(t+1)'s 8 stay in flight
    } else {
      VMCNT(0);
    }
    __builtin_amdgcn_sched_barrier(0);
    __builtin_amdgcn_s_barrier();
    __builtin_amdgcn_sched_barrier(0);

    const char* Ks = KV[buf];
    const char* Vt = KV[buf] + 16384;

    // ---- QK^T swapped: sc0/sc1 = K(keys 0-31 / 32-63) x Q -> P[key][q] ----
    f32x16 sc0, sc1;
#pragma unroll
    for (int e = 0; e < 16; ++e) { sc0[e] = 0.f; sc1[e] = 0.f; }
    const int kswz = (l31 & 7) << 4;
    __builtin_amdgcn_s_setprio(1);
#pragma unroll
    for (int c = 0; c < 8; ++c) {
      int off = c * 32 + hi5 * 16;
      bf16x8 k0f = *(const bf16x8*)(Ks + l31 * 256 + (off ^ kswz));
      bf16x8 k1f = *(const bf16x8*)(Ks + (32 + l31) * 256 + (off ^ kswz));
      sc0 = __builtin_amdgcn_mfma_f32_32x32x16_bf16(k0f, qB[c], sc0, 0, 0, 0);
      sc1 = __builtin_amdgcn_mfma_f32_32x32x16_bf16(k1f, qB[c], sc1, 0, 0, 0);
    }
    __builtin_amdgcn_s_setprio(0);

    // ---- causal mask (wave-uniform predicate) ----
    if (64 * (t + 1) > q0 + 32 * w) {
      int kb = t * 64 + hi5 * 4;
#pragma unroll
      for (int r = 0; r < 16; ++r) {
        int off = (r & 3) + 8 * (r >> 2);
        if (kb + off > qrow) sc0[r] = -3e38f;
        if (kb + 32 + off > qrow) sc1[r] = -3e38f;
      }
    }

    // ---- in-register online softmax (lane pair {l, l^32} owns q-row l31) ----
    float tv = -3e38f;
#pragma unroll
    for (int r = 0; r < 16; ++r) tv = fmaxf(tv, fmaxf(sc0[r], sc1[r]));
    tv = fmaxf(tv, __shfl_xor(tv, 32));
    if (!__all(tv <= m + 8.f)) {   // defer-max THR=8
      float mn = fmaxf(m, tv);
      float al = exp2f((m - mn) * kLog2e);
      m = mn;
      l *= al;
#pragma unroll
      for (int r = 0; r < 16; ++r) {
        float alr = __shfl(al, (r & 3) + 8 * (r >> 2) + 4 * hi5);
        acc[0][r] *= alr;
        acc[1][r] *= alr;
        acc[2][r] *= alr;
        acc[3][r] *= alr;
      }
    }
    float rs = 0.f;
#pragma unroll
    for (int r = 0; r < 16; ++r) {
      sc0[r] = exp2f((sc0[r] - m) * kLog2e);
      sc1[r] = exp2f((sc1[r] - m) * kLog2e);
      rs += sc0[r] + sc1[r];
    }
    rs += __shfl_xor(rs, 32);
    l += rs;

    // ---- P -> A-frag (cvt_pk + permlane32_swap) fused with PV MFMA ----
    __builtin_amdgcn_s_setprio(1);
#define PV_CHUNK(S, CI)                                                       \
    {                                                                         \
      unsigned p0 = pkbf(S[8 * ((CI) & 1) + 0], S[8 * ((CI) & 1) + 1]);       \
      unsigned p1 = pkbf(S[8 * ((CI) & 1) + 2], S[8 * ((CI) & 1) + 3]);       \
      unsigned p2 = pkbf(S[8 * ((CI) & 1) + 4], S[8 * ((CI) & 1) + 5]);       \
      unsigned p3 = pkbf(S[8 * ((CI) & 1) + 6], S[8 * ((CI) & 1) + 7]);       \
      asm("v_permlane32_swap_b32 %0, %1" : "+v"(p0), "+v"(p2));               \
      asm("v_permlane32_swap_b32 %0, %1" : "+v"(p1), "+v"(p3));               \
      union { unsigned u[4]; bf16x8 v; } pa;                                  \
      pa.u[0] = p0; pa.u[1] = p1; pa.u[2] = p2; pa.u[3] = p3;                 \
      int ko = (CI) * 32 + hi5 * 16;                                          \
      _Pragma("unroll") for (int dt = 0; dt < 4; ++dt) {                      \
        int d = dt * 32 + l31;                                                \
        bf16x8 vf = *(const bf16x8*)(Vt + d * 128 + (ko ^ ((d & 7) << 4)));   \
        acc[dt] =                                                             \
            __builtin_amdgcn_mfma_f32_32x32x16_bf16(pa.v, vf, acc[dt], 0, 0, 0); \
      }                                                                       \
    }
    PV_CHUNK(sc0, 0)
    PV_CHUNK(sc0, 1)
    PV_CHUNK(sc1, 2)
    PV_CHUNK(sc1, 3)
#undef PV_CHUNK
    __builtin_amdgcn_s_setprio(0);

    __builtin_amdgcn_sched_barrier(0);
    __builtin_amdgcn_s_barrier();   // all reads of KV[buf] done before overwrite
    __builtin_amdgcn_sched_barrier(0);
    buf ^= 1;
  }

  // ---- epilogue: out[q][d] = acc / l ----
  float linv = 1.f / l;
  const size_t obase = ((size_t)b * 1024 + q0 + w * 32) * 4096 + (size_t)hq * 128;
#pragma unroll
  for (int r = 0; r < 16; ++r) {
    int rq = (r & 3) + 8 * (r >> 2) + 4 * hi5;   // q row in [0,32)
    float ilr = __shfl(linv, rq);                // lane rq holds q=rq
    float* orow = out + obase + (size_t)rq * 4096 + l31;
    orow[0]  = acc[0][r] * ilr;
    orow[32] = acc[1][r] * ilr;
    orow[64] = acc[2][r] * ilr;
    orow[96] = acc[3][r] * ilr;
  }
#undef STAGE
}

// ---------------- fallback (small-ws path) ----------------
template <bool USE_TAB>
__global__ __launch_bounds__(256) void attn_k(
    const float* __restrict__ q, const float* __restrict__ k,
    const float* __restrict__ v, const float2* __restrict__ tab,
    float* __restrict__ out) {
  __shared__ short Ksf[64][kKPad];
  __shared__ short Vtf[kD][kVPad];
  __shared__ short Qbuf[64 * kKPad];
  const int tid = threadIdx.x;
  const int w = tid >> 6;
  const int lane = tid & 63;
  const int lrow = lane & 15;
  const int lk8 = (lane >> 4) * 8;
  const int qt = (int)gridDim.x - 1 - (int)blockIdx.x;
  const int hq = blockIdx.y;
  const int b = blockIdx.z;
  const int hkv = hq >> 2;
  const int q0 = qt * 64;
  const float* qb = q + (size_t)b * kS * 4096 + hq * kD;
  const float* kb = k + (size_t)b * kS * 1024 + hkv * kD;
  const float* vb = v + (size_t)b * kS * 1024 + hkv * kD;
#pragma unroll
  for (int it = 0; it < 16; ++it) {
    int pi = tid + it * 256;
    int row = pi >> 6, j = pi & 63;
    int pos = q0 + row;
    float x1 = qb[(size_t)pos * 4096 + j];
    float x2 = qb[(size_t)pos * 4096 + j + 64];
    float c, s;
    if (USE_TAB) { float2 t2 = tab[(pos << 6) + j]; c = t2.x; s = t2.y; }
    else { float ang = (float)pos * __expf(-(float)j * kFreqC); __sincosf(ang, &s, &c); }
    Qbuf[row * kKPad + j]      = f2bf((x1 * c - x2 * s) * kScale);
    Qbuf[row * kKPad + j + 64] = f2bf((x1 * s + x2 * c) * kScale);
  }
  __syncthreads();
  bf16x8 qf[4];
#pragma unroll
  for (int d = 0; d < 4; ++d)
    qf[d] = *(const bf16x8*)&Qbuf[(w * 16 + lrow) * kKPad + d * 32 + lk8];
  __syncthreads();
  short* myP = Qbuf + w * 16 * kVPad;
  float mS[4] = {-3e38f, -3e38f, -3e38f, -3e38f};
  float lS[4] = {0.f, 0.f, 0.f, 0.f};
  f32x4 acc[8];
#pragma unroll
  for (int dt = 0; dt < 8; ++dt) acc[dt] = f32x4{0.f, 0.f, 0.f, 0.f};
  for (int kt = 0; kt <= qt; ++kt) {
    const int k0 = kt * 64;
#pragma unroll
    for (int it = 0; it < 16; ++it) {
      int pi = tid + it * 256;
      int row = pi >> 6, j = pi & 63;
      int pos = k0 + row;
      float x1 = kb[(size_t)pos * 1024 + j];
      float x2 = kb[(size_t)pos * 1024 + j + 64];
      float c, s;
      if (USE_TAB) { float2 t2 = tab[(pos << 6) + j]; c = t2.x; s = t2.y; }
      else { float ang = (float)pos * __expf(-(float)j * kFreqC); __sincosf(ang, &s, &c); }
      Ksf[row][j]      = f2bf(x1 * c - x2 * s);
      Ksf[row][j + 64] = f2bf(x1 * s + x2 * c);
    }
#pragma unroll
    for (int it = 0; it < 8; ++it) {
      int f = (tid + it * 256) * 4;
      int row = f >> 7, col = f & 127;
      const float4 v4 = *(const float4*)(vb + (size_t)(k0 + row) * 1024 + col);
      Vtf[col + 0][row] = f2bf(v4.x);
      Vtf[col + 1][row] = f2bf(v4.y);
      Vtf[col + 2][row] = f2bf(v4.z);
      Vtf[col + 3][row] = f2bf(v4.w);
    }
    __syncthreads();
    f32x4 sc[4];
#pragma unroll
    for (int ct = 0; ct < 4; ++ct) {
      sc[ct] = f32x4{0.f, 0.f, 0.f, 0.f};
#pragma unroll
      for (int d = 0; d < 4; ++d) {
        bf16x8 kf = *(const bf16x8*)&Ksf[ct * 16 + lrow][d * 32 + lk8];
        sc[ct] = __builtin_amdgcn_mfma_f32_16x16x32_bf16(qf[d], kf, sc[ct], 0, 0, 0);
      }
    }
    if (kt == qt) {
#pragma unroll
      for (int ct = 0; ct < 4; ++ct) {
        int col = ct * 16 + lrow;
#pragma unroll
        for (int r = 0; r < 4; ++r) {
          int row = w * 16 + (lane >> 4) * 4 + r;
          if (col > row) sc[ct][r] = -3e38f;
        }
      }
    }
#pragma unroll
    for (int r = 0; r < 4; ++r) {
      float t = fmaxf(fmaxf(sc[0][r], sc[1][r]), fmaxf(sc[2][r], sc[3][r]));
      t = fmaxf(t, __shfl_xor(t, 1));
      t = fmaxf(t, __shfl_xor(t, 2));
      t = fmaxf(t, __shfl_xor(t, 4));
      t = fmaxf(t, __shfl_xor(t, 8));
      float mn = fmaxf(mS[r], t);
      float al = exp2f((mS[r] - mn) * kLog2e);
      float rs = 0.f;
#pragma unroll
      for (int ct = 0; ct < 4; ++ct) {
        float p = exp2f((sc[ct][r] - mn) * kLog2e);
        sc[ct][r] = p;
        rs += p;
      }
      rs += __shfl_xor(rs, 1);
      rs += __shfl_xor(rs, 2);
      rs += __shfl_xor(rs, 4);
      rs += __shfl_xor(rs, 8);
      lS[r] = lS[r] * al + rs;
      mS[r] = mn;
#pragma unroll
      for (int dt = 0; dt < 8; ++dt) acc[dt][r] *= al;
    }
#pragma unroll
    for (int ct = 0; ct < 4; ++ct)
#pragma unroll
      for (int r = 0; r < 4; ++r)
        myP[((lane >> 4) * 4 + r) * kVPad + ct * 16 + lrow] = f2bf(sc[ct][r]);
#pragma unroll
    for (int ks = 0; ks < 2; ++ks) {
      bf16x8 pf = *(const bf16x8*)&myP[lrow * kVPad + ks * 32 + lk8];
#pragma unroll
      for (int dt = 0; dt < 8; ++dt) {
        bf16x8 vf = *(const bf16x8*)&Vtf[dt * 16 + lrow][ks * 32 + lk8];
        acc[dt] = __builtin_amdgcn_mfma_f32_16x16x32_bf16(pf, vf, acc[dt], 0, 0, 0);
      }
    }
    __syncthreads();
  }
  float il[4];
#pragma unroll
  for (int r = 0; r < 4; ++r) il[r] = 1.f / lS[r];
  float* ob = out + ((size_t)b * kS + q0 + w * 16) * 4096 + hq * kD;
#pragma unroll
  for (int dt = 0; dt < 8; ++dt)
#pragma unroll
    for (int r = 0; r < 4; ++r)
      ob[((lane >> 4) * 4 + r) * 4096 + dt * 16 + lrow] = acc[dt][r] * il[r];
}

extern "C" void kernel_launch(void* const* d_in, const int* in_sizes, int n_in,
                              void* d_out, int out_size, void* d_ws, size_t ws_size,
                              hipStream_t stream) {
  const float* q = (const float*)d_in[0];
  const float* k = (const float*)d_in[1];
  const float* v = (const float*)d_in[2];
  float* out = (float*)d_out;

  if (ws_size >= kWsNeed) {
    float2* tab = (float2*)((char*)d_ws + kTabOff);
    short* Kp = (short*)((char*)d_ws + kKOff);
    short* Vp = (short*)((char*)d_ws + kVOff);
    prep_k<<<1792, 256, 0, stream>>>(k, v, Kp, Vp, tab);
    dim3 grid(8, 32, kB);  // 512 blocks = 2 per CU
    attn32_k<<<grid, 256, 0, stream>>>(q, Kp, Vp, tab, out);
  } else if (ws_size >= 512 * 1024) {
    float2* tab = (float2*)d_ws;
    rope_table_k<<<256, 256, 0, stream>>>(tab);
    dim3 grid(16, 32, kB);
    attn_k<true><<<grid, 256, 0, stream>>>(q, k, v, tab, out);
  } else {
    dim3 grid(16, 32, kB);
    attn_k<false><<<grid, 256, 0, stream>>>(q, k, v, nullptr, out);
  }
}